// Round 1
// baseline (2093.188 us; speedup 1.0000x reference)
//
#include <hip/hip_runtime.h>

#define NN 100000
#define NE 500000

typedef short v8s __attribute__((ext_vector_type(8)));
typedef float v4f __attribute__((ext_vector_type(4)));

__device__ __forceinline__ unsigned short f2bf(float f) {
    unsigned u = __float_as_uint(f);
    u += 0x7fffu + ((u >> 16) & 1u);
    return (unsigned short)(u >> 16);
}
__device__ __forceinline__ float bf2f(unsigned short h) {
    return __uint_as_float(((unsigned)h) << 16);
}
__device__ __forceinline__ unsigned pk2(float a, float b) {
    return (unsigned)f2bf(a) | ((unsigned)f2bf(b) << 16);
}
__device__ __forceinline__ float lo16(unsigned v) { return bf2f((unsigned short)(v & 0xffffu)); }
__device__ __forceinline__ float hi16(unsigned v) { return bf2f((unsigned short)(v >> 16)); }

// ---------------- dtype detector ----------------
// If dataset floats are bf16: element 2*tid of edge_rep is a sane value (~N(0,0.05)).
// If f32: ushort 2*tid is the low mantissa half of f32 word tid -> random bits.
__global__ void detect_k(const unsigned short* __restrict__ edgeR, int* __restrict__ flag) {
    __shared__ int cnt;
    const int tid = threadIdx.x;
    if (tid == 0) cnt = 0;
    __syncthreads();
    const float v = fabsf(bf2f(edgeR[2 * tid]));
    const int sane = (v > 1e-5f && v < 100.f) ? 1 : 0;
    atomicAdd(&cnt, sane);
    __syncthreads();
    if (tid == 0) *flag = (cnt >= 128) ? 1 : 0;
}

// ---------------- canonicalize inputs to bf16 ----------------
__global__ __launch_bounds__(256) void convert_k(const void* __restrict__ src,
    unsigned short* __restrict__ dst, const long n4, const int* __restrict__ flag)
{
    const long i = (long)blockIdx.x * 256 + threadIdx.x;
    if (i >= n4) return;
    if (*flag) {
        ((uint2*)dst)[i] = ((const uint2*)src)[i];
    } else {
        const float4 f = ((const float4*)src)[i];
        uint2 o; o.x = pk2(f.x, f.y); o.y = pk2(f.z, f.w);
        ((uint2*)dst)[i] = o;
    }
}

// ---------------- pack weights into MFMA B-fragment order ----------------
// wpk[((kt*ntn+ct)*64 + lane)*8 + j] = W[kt*32 + (lane>>4)*8 + j][ct*16 + (lane&15)]
__global__ __launch_bounds__(256) void pack_weights(
    const void* __restrict__ W1, const void* __restrict__ Wn1,
    const void* __restrict__ Wn2, const void* __restrict__ We1,
    const void* __restrict__ We2, unsigned short* __restrict__ wpk,
    const int* __restrict__ flag)
{
    const int i = blockIdx.x * 256 + threadIdx.x;
    if (i >= 163840) return;
    const void* W; int Nn; int li = i;
    if (i < 32768)       { W = W1;  Nn = 128; }
    else if (i < 65536)  { W = Wn1; Nn = 256; li -= 32768; }
    else if (i < 98304)  { W = Wn2; Nn = 128; li -= 65536; }
    else if (i < 131072) { W = We1; Nn = 256; li -= 98304; }
    else                 { W = We2; Nn = 128; li -= 131072; }
    const int ntn = Nn >> 4;
    const int j = li & 7, l = (li >> 3) & 63, tile = li >> 9;
    const int ct = tile % ntn, kt = tile / ntn;
    const int k = kt * 32 + (l >> 4) * 8 + j;
    const int n = ct * 16 + (l & 15);
    const int idx = k * Nn + n;
    wpk[i] = (*flag) ? ((const unsigned short*)W)[idx]
                     : f2bf(((const float*)W)[idx]);
}

// ---------------- kernel A: gather + concat GEMM (lvl_mlp_1) + edge GEMM (lift_mlp L1) ----------------
__global__ __launch_bounds__(256) void kernel_A(
    const unsigned short* __restrict__ node, const unsigned short* __restrict__ edge,
    const int* __restrict__ ep,
    const unsigned short* __restrict__ wpk1, const unsigned short* __restrict__ wpkE1,
    unsigned short* __restrict__ y1, unsigned short* __restrict__ w1,
    float* __restrict__ stats, const void* __restrict__ eps2p, const int* __restrict__ flag)
{
    __shared__ unsigned short X[64][264];   // stride 264 elems = 528B -> 2-way-free banks
    const int tid = threadIdx.x, wid = tid >> 6, lane = tid & 63;
    const int mrow = lane & 15, quad = lane >> 4;
    const long e0 = (long)blockIdx.x * 64;
    const int bin = blockIdx.x & 7;

    // stage [lift | edge] tile, 16 rows per wave
    for (int rr = 0; rr < 16; ++rr) {
        const int r = wid * 16 + rr;
        const long e = e0 + r;
        unsigned lp = 0, epk = 0;
        if (e < NE) {
            const int s = ep[e], t = ep[NE + e];
            const unsigned a = ((const unsigned*)(node + (size_t)s * 128))[lane];
            const unsigned b = ((const unsigned*)(node + (size_t)t * 128))[lane];
            epk = ((const unsigned*)(edge + (size_t)e * 128))[lane];
            lp = pk2(lo16(a) + lo16(b), hi16(a) + hi16(b));
        }
        *(unsigned*)&X[r][2 * lane] = lp;
        *(unsigned*)&X[r][128 + 2 * lane] = epk;
    }
    __syncthreads();

    // GEMM1: X[64x256] @ W_lvl1[256x128], wave owns cols [wid*32, wid*32+32)
    {
        v4f acc[4][2];
        #pragma unroll
        for (int rb = 0; rb < 4; ++rb)
            #pragma unroll
            for (int c = 0; c < 2; ++c)
                acc[rb][c] = (v4f){0.f, 0.f, 0.f, 0.f};
        const int ct0 = wid * 2;
        #pragma unroll
        for (int kt = 0; kt < 8; ++kt) {
            v8s a[4];
            #pragma unroll
            for (int rb = 0; rb < 4; ++rb)
                a[rb] = *(const v8s*)&X[rb * 16 + mrow][kt * 32 + quad * 8];
            #pragma unroll
            for (int c = 0; c < 2; ++c) {
                const v8s b = ((const v8s*)wpk1)[(kt * 8 + ct0 + c) * 64 + lane];
                #pragma unroll
                for (int rb = 0; rb < 4; ++rb)
                    acc[rb][c] = __builtin_amdgcn_mfma_f32_16x16x32_bf16(a[rb], b, acc[rb][c], 0, 0, 0);
            }
        }
        #pragma unroll
        for (int c = 0; c < 2; ++c) {
            const int col = (ct0 + c) * 16 + mrow;
            float sy = 0.f, sq = 0.f;
            #pragma unroll
            for (int rb = 0; rb < 4; ++rb) {
                #pragma unroll
                for (int r4 = 0; r4 < 4; ++r4) {
                    const float v = acc[rb][c][r4];
                    const long e = e0 + rb * 16 + quad * 4 + r4;
                    if (e < NE) y1[e * 128 + col] = f2bf(v);
                    sy += v; sq += v * v;
                }
            }
            sy += __shfl_xor(sy, 16); sy += __shfl_xor(sy, 32);
            sq += __shfl_xor(sq, 16); sq += __shfl_xor(sq, 32);
            if (quad == 0) {
                atomicAdd(&stats[bin * 1792 + col], sy);
                atomicAdd(&stats[bin * 1792 + 128 + col], sq);
            }
        }
    }
    __syncthreads();

    // rebuild edge_in = (1+eps2)*edge + lift into cols [0,128)
    const float e2 = 1.f + ((*flag) ? bf2f(((const unsigned short*)eps2p)[0])
                                    : ((const float*)eps2p)[0]);
    for (int rr = 0; rr < 16; ++rr) {
        const int r = wid * 16 + rr;
        const unsigned lp = *(const unsigned*)&X[r][2 * lane];
        const unsigned ee = *(const unsigned*)&X[r][128 + 2 * lane];
        *(unsigned*)&X[r][2 * lane] = pk2(fmaf(e2, lo16(ee), lo16(lp)),
                                          fmaf(e2, hi16(ee), hi16(lp)));
    }
    __syncthreads();

    // GEMM_e1: edge_in[64x128] @ W_e1[128x256], wave owns cols [wid*64, wid*64+64)
    {
        v4f acc[4][4];
        #pragma unroll
        for (int rb = 0; rb < 4; ++rb)
            #pragma unroll
            for (int c = 0; c < 4; ++c)
                acc[rb][c] = (v4f){0.f, 0.f, 0.f, 0.f};
        const int ct0 = wid * 4;
        #pragma unroll
        for (int kt = 0; kt < 4; ++kt) {
            v8s a[4];
            #pragma unroll
            for (int rb = 0; rb < 4; ++rb)
                a[rb] = *(const v8s*)&X[rb * 16 + mrow][kt * 32 + quad * 8];
            #pragma unroll
            for (int c = 0; c < 4; ++c) {
                const v8s b = ((const v8s*)wpkE1)[(kt * 16 + ct0 + c) * 64 + lane];
                #pragma unroll
                for (int rb = 0; rb < 4; ++rb)
                    acc[rb][c] = __builtin_amdgcn_mfma_f32_16x16x32_bf16(a[rb], b, acc[rb][c], 0, 0, 0);
            }
        }
        #pragma unroll
        for (int c = 0; c < 4; ++c) {
            const int col = (ct0 + c) * 16 + mrow;
            float sy = 0.f, sq = 0.f;
            #pragma unroll
            for (int rb = 0; rb < 4; ++rb) {
                #pragma unroll
                for (int r4 = 0; r4 < 4; ++r4) {
                    const float v = acc[rb][c][r4];
                    const long e = e0 + rb * 16 + quad * 4 + r4;
                    if (e < NE) w1[e * 256 + col] = f2bf(v);
                    sy += v; sq += v * v;
                }
            }
            sy += __shfl_xor(sy, 16); sy += __shfl_xor(sy, 32);
            sq += __shfl_xor(sq, 16); sq += __shfl_xor(sq, 32);
            if (quad == 0) {
                atomicAdd(&stats[bin * 1792 + 256 + col], sy);
                atomicAdd(&stats[bin * 1792 + 512 + col], sq);
            }
        }
    }
}

// ---------------- finalize BN: a = g*rsqrt(var+eps), b' = b - a*mu ----------------
__global__ void finalize_k(const float* __restrict__ stats, float* __restrict__ ab,
                           const void* __restrict__ g, const void* __restrict__ bb,
                           const int sOff, const int qOff, const int aOff, const int bOff,
                           const int n, const float invc, const int* __restrict__ flag)
{
    const int c = threadIdx.x;
    if (c >= n) return;
    float S = 0.f, Q = 0.f;
    for (int b = 0; b < 8; ++b) { S += stats[b * 1792 + sOff + c]; Q += stats[b * 1792 + qOff + c]; }
    const float mu = S * invc;
    const float var = Q * invc - mu * mu;
    const float gv = (*flag) ? bf2f(((const unsigned short*)g)[c]) : ((const float*)g)[c];
    const float bv = (*flag) ? bf2f(((const unsigned short*)bb)[c]) : ((const float*)bb)[c];
    const float a = gv * rsqrtf(var + 1e-5f);
    ab[aOff + c] = a;
    ab[bOff + c] = bv - a * mu;
}

// ---------------- scatter: acc[s]+=h, acc[t]+=h, h = relu(a1*y1+b1) ----------------
__global__ __launch_bounds__(256) void scatter_k(
    const unsigned short* __restrict__ y1, const int* __restrict__ ep,
    const float* __restrict__ ab, float* __restrict__ acc)
{
    const int gw = (blockIdx.x * 256 + threadIdx.x) >> 6;
    const int lane = threadIdx.x & 63;
    const int nw = (gridDim.x * 256) >> 6;
    const int c0 = 2 * lane;
    const float a0 = ab[c0], a1 = ab[c0 + 1];
    const float b0 = ab[128 + c0], b1 = ab[128 + c0 + 1];
    for (long e = gw; e < NE; e += nw) {
        const unsigned v = *(const unsigned*)(y1 + e * 128 + c0);
        const float h0 = fmaxf(fmaf(a0, lo16(v), b0), 0.f);
        const float h1 = fmaxf(fmaf(a1, hi16(v), b1), 0.f);
        const int s = ep[e], t = ep[NE + e];
        atomicAdd(&acc[(size_t)s * 128 + c0], h0);
        atomicAdd(&acc[(size_t)s * 128 + c0 + 1], h1);
        atomicAdd(&acc[(size_t)t * 128 + c0], h0);
        atomicAdd(&acc[(size_t)t * 128 + c0 + 1], h1);
    }
}

// ---------------- node MLP layer 1: ((1+eps1)*node + aggr) @ W_n1 [128->256] ----------------
__global__ __launch_bounds__(256) void gemm_node1(
    const unsigned short* __restrict__ node, const float* __restrict__ aggr,
    const unsigned short* __restrict__ wpk, unsigned short* __restrict__ z1,
    float* __restrict__ sS, float* __restrict__ sQ,
    const void* __restrict__ eps1p, const int* __restrict__ flag)
{
    __shared__ unsigned short X[64][136];
    const int tid = threadIdx.x, wid = tid >> 6, lane = tid & 63;
    const int mrow = lane & 15, quad = lane >> 4;
    const long r0 = (long)blockIdx.x * 64;
    const int bin = blockIdx.x & 7;
    const float ea = 1.f + ((*flag) ? bf2f(((const unsigned short*)eps1p)[0])
                                    : ((const float*)eps1p)[0]);
    for (int rr = 0; rr < 16; ++rr) {
        const int r = wid * 16 + rr;
        const long gr = r0 + r;
        unsigned o = 0;
        if (gr < NN) {
            const unsigned nr = ((const unsigned*)(node + (size_t)gr * 128))[lane];
            const float2 ag = ((const float2*)(aggr + (size_t)gr * 128))[lane];
            o = pk2(fmaf(ea, lo16(nr), ag.x), fmaf(ea, hi16(nr), ag.y));
        }
        *(unsigned*)&X[r][2 * lane] = o;
    }
    __syncthreads();
    v4f acc[4][4];
    #pragma unroll
    for (int rb = 0; rb < 4; ++rb)
        #pragma unroll
        for (int c = 0; c < 4; ++c)
            acc[rb][c] = (v4f){0.f, 0.f, 0.f, 0.f};
    const int ct0 = wid * 4;
    #pragma unroll
    for (int kt = 0; kt < 4; ++kt) {
        v8s a[4];
        #pragma unroll
        for (int rb = 0; rb < 4; ++rb)
            a[rb] = *(const v8s*)&X[rb * 16 + mrow][kt * 32 + quad * 8];
        #pragma unroll
        for (int c = 0; c < 4; ++c) {
            const v8s b = ((const v8s*)wpk)[(kt * 16 + ct0 + c) * 64 + lane];
            #pragma unroll
            for (int rb = 0; rb < 4; ++rb)
                acc[rb][c] = __builtin_amdgcn_mfma_f32_16x16x32_bf16(a[rb], b, acc[rb][c], 0, 0, 0);
        }
    }
    #pragma unroll
    for (int c = 0; c < 4; ++c) {
        const int col = (ct0 + c) * 16 + mrow;
        float sy = 0.f, sq = 0.f;
        #pragma unroll
        for (int rb = 0; rb < 4; ++rb) {
            #pragma unroll
            for (int r4 = 0; r4 < 4; ++r4) {
                const float v = acc[rb][c][r4];
                const long gr = r0 + rb * 16 + quad * 4 + r4;
                if (gr < NN) z1[gr * 256 + col] = f2bf(v);
                sy += v; sq += v * v;
            }
        }
        sy += __shfl_xor(sy, 16); sy += __shfl_xor(sy, 32);
        sq += __shfl_xor(sq, 16); sq += __shfl_xor(sq, 32);
        if (quad == 0) {
            atomicAdd(&sS[bin * 1792 + col], sy);
            atomicAdd(&sQ[bin * 1792 + col], sq);
        }
    }
}

// ---------------- generic layer-2 GEMM: relu(a*in+b) [rows,256] @ W [256->128] ----------------
__global__ __launch_bounds__(256) void gemm_k256(
    const unsigned short* __restrict__ in, const float* __restrict__ aab,
    const float* __restrict__ bab, const unsigned short* __restrict__ wpk,
    unsigned short* __restrict__ out, float* __restrict__ sS, float* __restrict__ sQ,
    const long rows)
{
    __shared__ unsigned short X[64][264];
    const int tid = threadIdx.x, wid = tid >> 6, lane = tid & 63;
    const int mrow = lane & 15, quad = lane >> 4;
    const long r0 = (long)blockIdx.x * 64;
    const int bin = blockIdx.x & 7;
    const float4 av = ((const float4*)aab)[lane];
    const float4 bv = ((const float4*)bab)[lane];
    for (int rr = 0; rr < 16; ++rr) {
        const int r = wid * 16 + rr;
        const long gr = r0 + r;
        ushort4 o = {0, 0, 0, 0};
        if (gr < rows) {
            const ushort4 w = *(const ushort4*)(in + gr * 256 + 4 * lane);
            o.x = f2bf(fmaxf(fmaf(av.x, bf2f(w.x), bv.x), 0.f));
            o.y = f2bf(fmaxf(fmaf(av.y, bf2f(w.y), bv.y), 0.f));
            o.z = f2bf(fmaxf(fmaf(av.z, bf2f(w.z), bv.z), 0.f));
            o.w = f2bf(fmaxf(fmaf(av.w, bf2f(w.w), bv.w), 0.f));
        }
        *(ushort4*)&X[r][4 * lane] = o;
    }
    __syncthreads();
    v4f acc[4][2];
    #pragma unroll
    for (int rb = 0; rb < 4; ++rb)
        #pragma unroll
        for (int c = 0; c < 2; ++c)
            acc[rb][c] = (v4f){0.f, 0.f, 0.f, 0.f};
    const int ct0 = wid * 2;
    #pragma unroll
    for (int kt = 0; kt < 8; ++kt) {
        v8s a[4];
        #pragma unroll
        for (int rb = 0; rb < 4; ++rb)
            a[rb] = *(const v8s*)&X[rb * 16 + mrow][kt * 32 + quad * 8];
        #pragma unroll
        for (int c = 0; c < 2; ++c) {
            const v8s b = ((const v8s*)wpk)[(kt * 8 + ct0 + c) * 64 + lane];
            #pragma unroll
            for (int rb = 0; rb < 4; ++rb)
                acc[rb][c] = __builtin_amdgcn_mfma_f32_16x16x32_bf16(a[rb], b, acc[rb][c], 0, 0, 0);
        }
    }
    #pragma unroll
    for (int c = 0; c < 2; ++c) {
        const int col = (ct0 + c) * 16 + mrow;
        float sy = 0.f, sq = 0.f;
        #pragma unroll
        for (int rb = 0; rb < 4; ++rb) {
            #pragma unroll
            for (int r4 = 0; r4 < 4; ++r4) {
                const float v = acc[rb][c][r4];
                const long gr = r0 + rb * 16 + quad * 4 + r4;
                if (gr < rows) out[gr * 128 + col] = f2bf(v);
                sy += v; sq += v * v;
            }
        }
        sy += __shfl_xor(sy, 16); sy += __shfl_xor(sy, 32);
        sq += __shfl_xor(sq, 16); sq += __shfl_xor(sq, 32);
        if (quad == 0) {
            atomicAdd(&sS[bin * 1792 + col], sy);
            atomicAdd(&sQ[bin * 1792 + col], sq);
        }
    }
}

// ---------------- final BN+ReLU apply -> d_out (dtype per flag) ----------------
__global__ __launch_bounds__(256) void final_k(
    const unsigned short* __restrict__ z2, const unsigned short* __restrict__ w2,
    const float* __restrict__ ab, void* __restrict__ out, const int* __restrict__ flag)
{
    const long p = (long)blockIdx.x * 256 + threadIdx.x;
    const long npn = (long)NN * 64;
    const long tot = npn + (long)NE * 64;
    if (p >= tot) return;
    long el, oe; const unsigned short* src; int abA, abB;
    if (p < npn) { el = p * 2; oe = el; src = z2; abA = 1536; abB = 1664; }
    else { el = (p - npn) * 2; oe = (long)NN * 128 + el; src = w2; abA = 1280; abB = 1408; }
    const int col = (int)(el & 127);
    const unsigned v = *(const unsigned*)(src + el);
    const float o0 = fmaxf(fmaf(ab[abA + col], lo16(v), ab[abB + col]), 0.f);
    const float o1 = fmaxf(fmaf(ab[abA + col + 1], hi16(v), ab[abB + col + 1]), 0.f);
    if (*flag) {
        *(unsigned*)((unsigned short*)out + oe) = pk2(o0, o1);
    } else {
        float2 f; f.x = o0; f.y = o1;
        *(float2*)((float*)out + oe) = f;
    }
}

extern "C" void kernel_launch(void* const* d_in, const int* in_sizes, int n_in,
                              void* d_out, int out_size, void* d_ws, size_t ws_size,
                              hipStream_t stream)
{
    (void)in_sizes; (void)n_in; (void)out_size; (void)ws_size;
    const unsigned short* edgeR = (const unsigned short*)d_in[1];
    const int* ep = (const int*)d_in[2];

    char* ws = (char*)d_ws;
    unsigned short* wpk = (unsigned short*)ws;                     // 327,680 B
    float* stats = (float*)(ws + 327680);                          // 8*1792*4 = 57,344 B
    float* ab    = (float*)(ws + 385024);                          // 7,168 B
    int* flag    = (int*)(ws + 392192);                            // 256 B
    float* acc   = (float*)(ws + 392448);                          // 51.2 MB
    unsigned short* nodeC = (unsigned short*)(ws + 51592448);      // 25.6 MB
    unsigned short* edgeC = (unsigned short*)(ws + 77192448);      // 128 MB
    unsigned short* y1    = (unsigned short*)(ws + 205192448);     // 128 MB
    unsigned short* w1    = (unsigned short*)(ws + 333192448);     // 256 MB  (end 589.2 MB)
    unsigned short* w2 = edgeC;          // alias: edgeC dead after kernel_A
    unsigned short* z1 = y1;             // alias: y1 dead after scatter
    unsigned short* z2 = y1 + 25600000;  // within y1 region, after z1

    const unsigned short* wpk1  = wpk;
    const unsigned short* wpkN1 = wpk + 32768;
    const unsigned short* wpkN2 = wpk + 65536;
    const unsigned short* wpkE1 = wpk + 98304;
    const unsigned short* wpkE2 = wpk + 131072;

    detect_k<<<1, 256, 0, stream>>>(edgeR, flag);
    hipMemsetAsync(stats, 0, 57344, stream);
    hipMemsetAsync(acc, 0, (size_t)NN * 128 * 4, stream);
    convert_k<<<12500, 256, 0, stream>>>(d_in[0], nodeC, 3200000, flag);
    convert_k<<<62500, 256, 0, stream>>>(d_in[1], edgeC, 16000000, flag);
    pack_weights<<<640, 256, 0, stream>>>(d_in[3], d_in[6], d_in[9], d_in[12], d_in[15], wpk, flag);

    kernel_A<<<7813, 256, 0, stream>>>(nodeC, edgeC, ep, wpk1, wpkE1, y1, w1, stats, d_in[19], flag);
    finalize_k<<<1, 128, 0, stream>>>(stats, ab, d_in[4], d_in[5], 0, 128, 0, 128, 128, 1.f / NE, flag);
    finalize_k<<<1, 256, 0, stream>>>(stats, ab, d_in[13], d_in[14], 256, 512, 256, 512, 256, 1.f / NE, flag);

    scatter_k<<<2048, 256, 0, stream>>>(y1, ep, ab, acc);

    gemm_k256<<<7813, 256, 0, stream>>>(w1, ab + 256, ab + 512, wpkE2, w2, stats + 1280, stats + 1408, (long)NE);
    finalize_k<<<1, 128, 0, stream>>>(stats, ab, d_in[16], d_in[17], 1280, 1408, 1280, 1408, 128, 1.f / NE, flag);

    gemm_node1<<<1563, 256, 0, stream>>>(nodeC, acc, wpkN1, z1, stats + 768, stats + 1024, d_in[18], flag);
    finalize_k<<<1, 256, 0, stream>>>(stats, ab, d_in[7], d_in[8], 768, 1024, 768, 1024, 256, 1.f / NN, flag);

    gemm_k256<<<1563, 256, 0, stream>>>(z1, ab + 768, ab + 1024, wpkN2, z2, stats + 1536, stats + 1664, (long)NN);
    finalize_k<<<1, 128, 0, stream>>>(stats, ab, d_in[10], d_in[11], 1536, 1664, 1536, 1664, 128, 1.f / NN, flag);

    final_k<<<150000, 256, 0, stream>>>(z2, w2, ab, d_out, flag);
}

// Round 2
// 2049.940 us; speedup vs baseline: 1.0211x; 1.0211x over previous
//
#include <hip/hip_runtime.h>

#define NN 100000
#define NE 500000

typedef short v8s __attribute__((ext_vector_type(8)));
typedef float v4f __attribute__((ext_vector_type(4)));

__device__ __forceinline__ unsigned short f2bf(float f) {
    unsigned u = __float_as_uint(f);
    u += 0x7fffu + ((u >> 16) & 1u);
    return (unsigned short)(u >> 16);
}
__device__ __forceinline__ float bf2f(unsigned short h) {
    return __uint_as_float(((unsigned)h) << 16);
}
__device__ __forceinline__ unsigned pk2(float a, float b) {
    return (unsigned)f2bf(a) | ((unsigned)f2bf(b) << 16);
}
__device__ __forceinline__ float lo16(unsigned v) { return bf2f((unsigned short)(v & 0xffffu)); }
__device__ __forceinline__ float hi16(unsigned v) { return bf2f((unsigned short)(v >> 16)); }

// load channels (2*lane, 2*lane+1) of row `row` of a [rows,128] float tensor
// stored as bf16 (f=1) or f32 (f=0); returns packed bf16 pair.
__device__ __forceinline__ unsigned load2(const void* base, long row, int lane, int f) {
    if (f) return ((const unsigned*)base)[row * 64 + lane];
    const float2 v = ((const float2*)base)[row * 64 + lane];
    return pk2(v.x, v.y);
}

// ---------------- dtype detector ----------------
__global__ void detect_k(const unsigned short* __restrict__ edgeR, int* __restrict__ flag) {
    __shared__ int cnt;
    const int tid = threadIdx.x;
    if (tid == 0) cnt = 0;
    __syncthreads();
    const float v = fabsf(bf2f(edgeR[2 * tid]));
    const int sane = (v > 1e-5f && v < 100.f) ? 1 : 0;
    atomicAdd(&cnt, sane);
    __syncthreads();
    if (tid == 0) *flag = (cnt >= 128) ? 1 : 0;
}

// ---------------- CSR build: histogram -> scan -> fill ----------------
__global__ __launch_bounds__(256) void hist_k(const int* __restrict__ ep, int* __restrict__ deg) {
    const int i = blockIdx.x * 256 + threadIdx.x;
    if (i < 2 * NE) atomicAdd(&deg[ep[i]], 1);
}

__global__ __launch_bounds__(1024) void scan_k(int* __restrict__ degcur, int* __restrict__ rowptr) {
    __shared__ int sd[1024];
    const int t = threadIdx.x;
    const int base = t * 98;
    int sum = 0;
    for (int i = 0; i < 98; ++i) {
        const int idx = base + i;
        if (idx < NN) sum += degcur[idx];
    }
    sd[t] = sum;
    __syncthreads();
    for (int off = 1; off < 1024; off <<= 1) {
        const int v = (t >= off) ? sd[t - off] : 0;
        __syncthreads();
        sd[t] += v;
        __syncthreads();
    }
    int run = sd[t] - sum;   // exclusive prefix of this chunk
    for (int i = 0; i < 98; ++i) {
        const int idx = base + i;
        if (idx < NN) {
            const int d = degcur[idx];   // read BEFORE overwrite
            rowptr[idx] = run;
            degcur[idx] = run;           // becomes the fill cursor
            run += d;
        }
    }
    if (t == 0) rowptr[NN] = 2 * NE;
}

__global__ __launch_bounds__(256) void fill_k(const int* __restrict__ ep,
                                              int* __restrict__ cursor, int* __restrict__ csr) {
    const int i = blockIdx.x * 256 + threadIdx.x;
    if (i >= 2 * NE) return;
    const int n = ep[i];
    const int pos = atomicAdd(&cursor[n], 1);
    csr[pos] = (i < NE) ? i : (i - NE);
}

// ---------------- pack weights into MFMA B-fragment order ----------------
__global__ __launch_bounds__(256) void pack_weights(
    const void* __restrict__ W1, const void* __restrict__ Wn1,
    const void* __restrict__ Wn2, const void* __restrict__ We1,
    const void* __restrict__ We2, unsigned short* __restrict__ wpk,
    const int* __restrict__ flag)
{
    const int i = blockIdx.x * 256 + threadIdx.x;
    if (i >= 163840) return;
    const void* W; int Nn; int li = i;
    if (i < 32768)       { W = W1;  Nn = 128; }
    else if (i < 65536)  { W = Wn1; Nn = 256; li -= 32768; }
    else if (i < 98304)  { W = Wn2; Nn = 128; li -= 65536; }
    else if (i < 131072) { W = We1; Nn = 256; li -= 98304; }
    else                 { W = We2; Nn = 128; li -= 131072; }
    const int ntn = Nn >> 4;
    const int j = li & 7, l = (li >> 3) & 63, tile = li >> 9;
    const int ct = tile % ntn, kt = tile / ntn;
    const int k = kt * 32 + (l >> 4) * 8 + j;
    const int n = ct * 16 + (l & 15);
    const int idx = k * Nn + n;
    wpk[i] = (*flag) ? ((const unsigned short*)W)[idx]
                     : f2bf(((const float*)W)[idx]);
}

// ---------------- kernel A: gather + concat GEMM (lvl_mlp_1) + edge GEMM (lift_mlp L1) ----------------
__global__ __launch_bounds__(256) void kernel_A(
    const void* __restrict__ node, const void* __restrict__ edge,
    const int* __restrict__ ep,
    const unsigned short* __restrict__ wpk1, const unsigned short* __restrict__ wpkE1,
    unsigned short* __restrict__ y1, unsigned short* __restrict__ w1,
    float* __restrict__ stats, const void* __restrict__ eps2p, const int* __restrict__ flag)
{
    __shared__ unsigned short X[64][264];
    const int tid = threadIdx.x, wid = tid >> 6, lane = tid & 63;
    const int mrow = lane & 15, quad = lane >> 4;
    const long e0 = (long)blockIdx.x * 64;
    const int bin = blockIdx.x & 7;
    const int f = *flag;

    for (int rr = 0; rr < 16; ++rr) {
        const int r = wid * 16 + rr;
        const long e = e0 + r;
        unsigned lp = 0, epk = 0;
        if (e < NE) {
            const int s = ep[e], t = ep[NE + e];
            const unsigned a = load2(node, s, lane, f);
            const unsigned b = load2(node, t, lane, f);
            epk = load2(edge, e, lane, f);
            lp = pk2(lo16(a) + lo16(b), hi16(a) + hi16(b));
        }
        *(unsigned*)&X[r][2 * lane] = lp;
        *(unsigned*)&X[r][128 + 2 * lane] = epk;
    }
    __syncthreads();

    // GEMM1: X[64x256] @ W_lvl1[256x128]
    {
        v4f acc[4][2];
        #pragma unroll
        for (int rb = 0; rb < 4; ++rb)
            #pragma unroll
            for (int c = 0; c < 2; ++c)
                acc[rb][c] = (v4f){0.f, 0.f, 0.f, 0.f};
        const int ct0 = wid * 2;
        #pragma unroll
        for (int kt = 0; kt < 8; ++kt) {
            v8s a[4];
            #pragma unroll
            for (int rb = 0; rb < 4; ++rb)
                a[rb] = *(const v8s*)&X[rb * 16 + mrow][kt * 32 + quad * 8];
            #pragma unroll
            for (int c = 0; c < 2; ++c) {
                const v8s b = ((const v8s*)wpk1)[(kt * 8 + ct0 + c) * 64 + lane];
                #pragma unroll
                for (int rb = 0; rb < 4; ++rb)
                    acc[rb][c] = __builtin_amdgcn_mfma_f32_16x16x32_bf16(a[rb], b, acc[rb][c], 0, 0, 0);
            }
        }
        #pragma unroll
        for (int c = 0; c < 2; ++c) {
            const int col = (ct0 + c) * 16 + mrow;
            float sy = 0.f, sq = 0.f;
            #pragma unroll
            for (int rb = 0; rb < 4; ++rb) {
                #pragma unroll
                for (int r4 = 0; r4 < 4; ++r4) {
                    const float v = acc[rb][c][r4];
                    const long e = e0 + rb * 16 + quad * 4 + r4;
                    if (e < NE) y1[e * 128 + col] = f2bf(v);
                    sy += v; sq += v * v;
                }
            }
            sy += __shfl_xor(sy, 16); sy += __shfl_xor(sy, 32);
            sq += __shfl_xor(sq, 16); sq += __shfl_xor(sq, 32);
            if (quad == 0) {
                atomicAdd(&stats[bin * 1792 + col], sy);
                atomicAdd(&stats[bin * 1792 + 128 + col], sq);
            }
        }
    }
    __syncthreads();

    // rebuild edge_in = (1+eps2)*edge + lift into cols [0,128)
    const float e2 = 1.f + (f ? bf2f(((const unsigned short*)eps2p)[0])
                              : ((const float*)eps2p)[0]);
    for (int rr = 0; rr < 16; ++rr) {
        const int r = wid * 16 + rr;
        const unsigned lp = *(const unsigned*)&X[r][2 * lane];
        const unsigned ee = *(const unsigned*)&X[r][128 + 2 * lane];
        *(unsigned*)&X[r][2 * lane] = pk2(fmaf(e2, lo16(ee), lo16(lp)),
                                          fmaf(e2, hi16(ee), hi16(lp)));
    }
    __syncthreads();

    // GEMM_e1: edge_in[64x128] @ W_e1[128x256]
    {
        v4f acc[4][4];
        #pragma unroll
        for (int rb = 0; rb < 4; ++rb)
            #pragma unroll
            for (int c = 0; c < 4; ++c)
                acc[rb][c] = (v4f){0.f, 0.f, 0.f, 0.f};
        const int ct0 = wid * 4;
        #pragma unroll
        for (int kt = 0; kt < 4; ++kt) {
            v8s a[4];
            #pragma unroll
            for (int rb = 0; rb < 4; ++rb)
                a[rb] = *(const v8s*)&X[rb * 16 + mrow][kt * 32 + quad * 8];
            #pragma unroll
            for (int c = 0; c < 4; ++c) {
                const v8s b = ((const v8s*)wpkE1)[(kt * 16 + ct0 + c) * 64 + lane];
                #pragma unroll
                for (int rb = 0; rb < 4; ++rb)
                    acc[rb][c] = __builtin_amdgcn_mfma_f32_16x16x32_bf16(a[rb], b, acc[rb][c], 0, 0, 0);
            }
        }
        #pragma unroll
        for (int c = 0; c < 4; ++c) {
            const int col = (ct0 + c) * 16 + mrow;
            float sy = 0.f, sq = 0.f;
            #pragma unroll
            for (int rb = 0; rb < 4; ++rb) {
                #pragma unroll
                for (int r4 = 0; r4 < 4; ++r4) {
                    const float v = acc[rb][c][r4];
                    const long e = e0 + rb * 16 + quad * 4 + r4;
                    if (e < NE) w1[e * 256 + col] = f2bf(v);
                    sy += v; sq += v * v;
                }
            }
            sy += __shfl_xor(sy, 16); sy += __shfl_xor(sy, 32);
            sq += __shfl_xor(sq, 16); sq += __shfl_xor(sq, 32);
            if (quad == 0) {
                atomicAdd(&stats[bin * 1792 + 256 + col], sy);
                atomicAdd(&stats[bin * 1792 + 512 + col], sq);
            }
        }
    }
}

// ---------------- finalize BN ----------------
__global__ void finalize_k(const float* __restrict__ stats, float* __restrict__ ab,
                           const void* __restrict__ g, const void* __restrict__ bb,
                           const int sOff, const int qOff, const int aOff, const int bOff,
                           const int n, const float invc, const int* __restrict__ flag)
{
    const int c = threadIdx.x;
    if (c >= n) return;
    float S = 0.f, Q = 0.f;
    for (int b = 0; b < 8; ++b) { S += stats[b * 1792 + sOff + c]; Q += stats[b * 1792 + qOff + c]; }
    const float mu = S * invc;
    const float var = Q * invc - mu * mu;
    const float gv = (*flag) ? bf2f(((const unsigned short*)g)[c]) : ((const float*)g)[c];
    const float bv = (*flag) ? bf2f(((const unsigned short*)bb)[c]) : ((const float*)bb)[c];
    const float a = gv * rsqrtf(var + 1e-5f);
    ab[aOff + c] = a;
    ab[bOff + c] = bv - a * mu;
}

// ---------------- node MLP layer 1 with fused CSR gather ----------------
// node_in = (1+eps1)*node + sum_{incident e} relu(a*y1[e]+b);  z1 = node_in @ W_n1
__global__ __launch_bounds__(256) void gemm_node1(
    const void* __restrict__ node, const unsigned short* __restrict__ y1,
    const int* __restrict__ rowptr, const int* __restrict__ csr,
    const unsigned short* __restrict__ wpk, unsigned short* __restrict__ z1,
    float* __restrict__ sS, float* __restrict__ sQ,
    const void* __restrict__ eps1p, const float* __restrict__ ab,
    const int* __restrict__ flag)
{
    __shared__ unsigned short X[64][136];
    const int tid = threadIdx.x, wid = tid >> 6, lane = tid & 63;
    const int mrow = lane & 15, quad = lane >> 4;
    const long r0 = (long)blockIdx.x * 64;
    const int bin = blockIdx.x & 7;
    const int f = *flag;
    const float ea = 1.f + (f ? bf2f(((const unsigned short*)eps1p)[0])
                              : ((const float*)eps1p)[0]);
    const int c0 = 2 * lane;
    const float a0 = ab[c0], a1 = ab[c0 + 1];
    const float b0 = ab[128 + c0], b1 = ab[128 + c0 + 1];

    for (int rr = 0; rr < 16; ++rr) {
        const int r = wid * 16 + rr;
        const long gr = r0 + r;
        unsigned o = 0;
        if (gr < NN) {
            float s0 = 0.f, s1 = 0.f;
            const int beg = rowptr[gr], end = rowptr[gr + 1];
            for (int i = beg; i < end; ++i) {
                const int e = csr[i];
                const unsigned v = ((const unsigned*)y1)[(size_t)e * 64 + lane];
                s0 += fmaxf(fmaf(a0, lo16(v), b0), 0.f);
                s1 += fmaxf(fmaf(a1, hi16(v), b1), 0.f);
            }
            const unsigned nr = load2(node, gr, lane, f);
            o = pk2(fmaf(ea, lo16(nr), s0), fmaf(ea, hi16(nr), s1));
        }
        *(unsigned*)&X[r][2 * lane] = o;
    }
    __syncthreads();

    v4f acc[4][4];
    #pragma unroll
    for (int rb = 0; rb < 4; ++rb)
        #pragma unroll
        for (int c = 0; c < 4; ++c)
            acc[rb][c] = (v4f){0.f, 0.f, 0.f, 0.f};
    const int ct0 = wid * 4;
    #pragma unroll
    for (int kt = 0; kt < 4; ++kt) {
        v8s a[4];
        #pragma unroll
        for (int rb = 0; rb < 4; ++rb)
            a[rb] = *(const v8s*)&X[rb * 16 + mrow][kt * 32 + quad * 8];
        #pragma unroll
        for (int c = 0; c < 4; ++c) {
            const v8s b = ((const v8s*)wpk)[(kt * 16 + ct0 + c) * 64 + lane];
            #pragma unroll
            for (int rb = 0; rb < 4; ++rb)
                acc[rb][c] = __builtin_amdgcn_mfma_f32_16x16x32_bf16(a[rb], b, acc[rb][c], 0, 0, 0);
        }
    }
    #pragma unroll
    for (int c = 0; c < 4; ++c) {
        const int col = (ct0 + c) * 16 + mrow;
        float sy = 0.f, sq = 0.f;
        #pragma unroll
        for (int rb = 0; rb < 4; ++rb) {
            #pragma unroll
            for (int r4 = 0; r4 < 4; ++r4) {
                const float v = acc[rb][c][r4];
                const long gr = r0 + rb * 16 + quad * 4 + r4;
                if (gr < NN) z1[gr * 256 + col] = f2bf(v);
                sy += v; sq += v * v;
            }
        }
        sy += __shfl_xor(sy, 16); sy += __shfl_xor(sy, 32);
        sq += __shfl_xor(sq, 16); sq += __shfl_xor(sq, 32);
        if (quad == 0) {
            atomicAdd(&sS[bin * 1792 + col], sy);
            atomicAdd(&sQ[bin * 1792 + col], sq);
        }
    }
}

// ---------------- generic layer-2 GEMM: relu(a*in+b) [rows,256] @ W [256->128] ----------------
__global__ __launch_bounds__(256) void gemm_k256(
    const unsigned short* __restrict__ in, const float* __restrict__ aab,
    const float* __restrict__ bab, const unsigned short* __restrict__ wpk,
    unsigned short* __restrict__ out, float* __restrict__ sS, float* __restrict__ sQ,
    const long rows)
{
    __shared__ unsigned short X[64][264];
    const int tid = threadIdx.x, wid = tid >> 6, lane = tid & 63;
    const int mrow = lane & 15, quad = lane >> 4;
    const long r0 = (long)blockIdx.x * 64;
    const int bin = blockIdx.x & 7;
    const float4 av = ((const float4*)aab)[lane];
    const float4 bv = ((const float4*)bab)[lane];
    for (int rr = 0; rr < 16; ++rr) {
        const int r = wid * 16 + rr;
        const long gr = r0 + r;
        ushort4 o = {0, 0, 0, 0};
        if (gr < rows) {
            const ushort4 w = *(const ushort4*)(in + gr * 256 + 4 * lane);
            o.x = f2bf(fmaxf(fmaf(av.x, bf2f(w.x), bv.x), 0.f));
            o.y = f2bf(fmaxf(fmaf(av.y, bf2f(w.y), bv.y), 0.f));
            o.z = f2bf(fmaxf(fmaf(av.z, bf2f(w.z), bv.z), 0.f));
            o.w = f2bf(fmaxf(fmaf(av.w, bf2f(w.w), bv.w), 0.f));
        }
        *(ushort4*)&X[r][4 * lane] = o;
    }
    __syncthreads();
    v4f acc[4][2];
    #pragma unroll
    for (int rb = 0; rb < 4; ++rb)
        #pragma unroll
        for (int c = 0; c < 2; ++c)
            acc[rb][c] = (v4f){0.f, 0.f, 0.f, 0.f};
    const int ct0 = wid * 2;
    #pragma unroll
    for (int kt = 0; kt < 8; ++kt) {
        v8s a[4];
        #pragma unroll
        for (int rb = 0; rb < 4; ++rb)
            a[rb] = *(const v8s*)&X[rb * 16 + mrow][kt * 32 + quad * 8];
        #pragma unroll
        for (int c = 0; c < 2; ++c) {
            const v8s b = ((const v8s*)wpk)[(kt * 8 + ct0 + c) * 64 + lane];
            #pragma unroll
            for (int rb = 0; rb < 4; ++rb)
                acc[rb][c] = __builtin_amdgcn_mfma_f32_16x16x32_bf16(a[rb], b, acc[rb][c], 0, 0, 0);
        }
    }
    #pragma unroll
    for (int c = 0; c < 2; ++c) {
        const int col = (ct0 + c) * 16 + mrow;
        float sy = 0.f, sq = 0.f;
        #pragma unroll
        for (int rb = 0; rb < 4; ++rb) {
            #pragma unroll
            for (int r4 = 0; r4 < 4; ++r4) {
                const float v = acc[rb][c][r4];
                const long gr = r0 + rb * 16 + quad * 4 + r4;
                if (gr < rows) out[gr * 128 + col] = f2bf(v);
                sy += v; sq += v * v;
            }
        }
        sy += __shfl_xor(sy, 16); sy += __shfl_xor(sy, 32);
        sq += __shfl_xor(sq, 16); sq += __shfl_xor(sq, 32);
        if (quad == 0) {
            atomicAdd(&sS[bin * 1792 + col], sy);
            atomicAdd(&sQ[bin * 1792 + col], sq);
        }
    }
}

// ---------------- final BN+ReLU apply -> d_out ----------------
__global__ __launch_bounds__(256) void final_k(
    const unsigned short* __restrict__ z2, const unsigned short* __restrict__ w2,
    const float* __restrict__ ab, void* __restrict__ out, const int* __restrict__ flag)
{
    const long p = (long)blockIdx.x * 256 + threadIdx.x;
    const long npn = (long)NN * 64;
    const long tot = npn + (long)NE * 64;
    if (p >= tot) return;
    long el, oe; const unsigned short* src; int abA, abB;
    if (p < npn) { el = p * 2; oe = el; src = z2; abA = 1536; abB = 1664; }
    else { el = (p - npn) * 2; oe = (long)NN * 128 + el; src = w2; abA = 1280; abB = 1408; }
    const int col = (int)(el & 127);
    const unsigned v = *(const unsigned*)(src + el);
    const float o0 = fmaxf(fmaf(ab[abA + col], lo16(v), ab[abB + col]), 0.f);
    const float o1 = fmaxf(fmaf(ab[abA + col + 1], hi16(v), ab[abB + col + 1]), 0.f);
    if (*flag) {
        *(unsigned*)((unsigned short*)out + oe) = pk2(o0, o1);
    } else {
        float2 f; f.x = o0; f.y = o1;
        *(float2*)((float*)out + oe) = f;
    }
}

extern "C" void kernel_launch(void* const* d_in, const int* in_sizes, int n_in,
                              void* d_out, int out_size, void* d_ws, size_t ws_size,
                              hipStream_t stream)
{
    (void)in_sizes; (void)n_in; (void)out_size; (void)ws_size;
    const unsigned short* edgeR = (const unsigned short*)d_in[1];
    const int* ep = (const int*)d_in[2];

    char* ws = (char*)d_ws;
    unsigned short* wpk = (unsigned short*)ws;                      // 327,680 B
    float* stats   = (float*)(ws + 327680);                         // 57,344 B
    float* ab      = (float*)(ws + 385024);                         // 7,168 B
    int*   flag    = (int*)(ws + 392192);                           // 256 B
    int*   rowptr  = (int*)(ws + 392448);                           // 400,128 B
    int*   cursor  = (int*)(ws + 792576);                           // 400,128 B (deg -> fill cursor)
    int*   csr     = (int*)(ws + 1192704);                          // 4,000,000 B
    unsigned short* y1 = (unsigned short*)(ws + 5192704);           // 128 MB
    unsigned short* w1 = (unsigned short*)(ws + 133192704);         // 256 MB
    unsigned short* w2 = (unsigned short*)(ws + 389192704);         // 128 MB
    unsigned short* z1 = (unsigned short*)(ws + 517192704);         // 51.2 MB
    unsigned short* z2 = (unsigned short*)(ws + 568392704);         // 25.6 MB (end ~594 MB)

    const unsigned short* wpk1  = wpk;
    const unsigned short* wpkN1 = wpk + 32768;
    const unsigned short* wpkN2 = wpk + 65536;
    const unsigned short* wpkE1 = wpk + 98304;
    const unsigned short* wpkE2 = wpk + 131072;

    detect_k<<<1, 256, 0, stream>>>(edgeR, flag);
    hipMemsetAsync(stats, 0, 57344, stream);
    hipMemsetAsync(cursor, 0, 400000, stream);

    // CSR build (depends only on ep)
    hist_k<<<3907, 256, 0, stream>>>(ep, cursor);
    scan_k<<<1, 1024, 0, stream>>>(cursor, rowptr);
    fill_k<<<3907, 256, 0, stream>>>(ep, cursor, csr);

    pack_weights<<<640, 256, 0, stream>>>(d_in[3], d_in[6], d_in[9], d_in[12], d_in[15], wpk, flag);

    kernel_A<<<7813, 256, 0, stream>>>(d_in[0], d_in[1], ep, wpk1, wpkE1, y1, w1, stats, d_in[19], flag);
    finalize_k<<<1, 128, 0, stream>>>(stats, ab, d_in[4], d_in[5], 0, 128, 0, 128, 128, 1.f / NE, flag);
    finalize_k<<<1, 256, 0, stream>>>(stats, ab, d_in[13], d_in[14], 256, 512, 256, 512, 256, 1.f / NE, flag);

    // node branch first: y1 is still L3-warm for the CSR gather
    gemm_node1<<<1563, 256, 0, stream>>>(d_in[0], y1, rowptr, csr, wpkN1, z1,
                                         stats + 768, stats + 1024, d_in[18], ab, flag);
    finalize_k<<<1, 256, 0, stream>>>(stats, ab, d_in[7], d_in[8], 768, 1024, 768, 1024, 256, 1.f / NN, flag);

    gemm_k256<<<1563, 256, 0, stream>>>(z1, ab + 768, ab + 1024, wpkN2, z2,
                                        stats + 1536, stats + 1664, (long)NN);
    finalize_k<<<1, 128, 0, stream>>>(stats, ab, d_in[10], d_in[11], 1536, 1664, 1536, 1664, 128, 1.f / NN, flag);

    // edge branch
    gemm_k256<<<7813, 256, 0, stream>>>(w1, ab + 256, ab + 512, wpkE2, w2,
                                        stats + 1280, stats + 1408, (long)NE);
    finalize_k<<<1, 128, 0, stream>>>(stats, ab, d_in[16], d_in[17], 1280, 1408, 1280, 1408, 128, 1.f / NE, flag);

    final_k<<<150000, 256, 0, stream>>>(z2, w2, ab, d_out, flag);
}